// Round 13
// baseline (439.357 us; speedup 1.0000x reference)
//
#include <hip/hip_runtime.h>
#include <math.h>

#define BB 16
#define CC 512
#define LL 1024
#define NCONV 4
#define KW 7
#define NH 8
#define DH 64

typedef short short8 __attribute__((ext_vector_type(8)));
typedef float f32x4  __attribute__((ext_vector_type(4)));

union bfpack2 { __bf16 h[2]; unsigned u; };
union bfpack4 { __bf16 h[4]; uint2 v; };
union bfpack8 { __bf16 h[8]; uint4 v; };

// async global->LDS, 16B per lane. LDS dest is wave-uniform base + lane*16.
__device__ __forceinline__ void gload_lds16(const void* g, void* l) {
    __builtin_amdgcn_global_load_lds(
        (const __attribute__((address_space(1))) void*)g,
        (__attribute__((address_space(3))) void*)l, 16, 0, 0);
}

// ---------------------------------------------------------------- fused weight prep:
// pw_w(4S) | w_kv(2S) | w_q(S) | ffn1_w(S) | ffn2_w(S) -> contiguous bf16 at out
__global__ __launch_bounds__(256) void wprep_kernel(
    const float* __restrict__ pw, const float* __restrict__ wkv,
    const float* __restrict__ wq, const float* __restrict__ f1,
    const float* __restrict__ f2, __bf16* __restrict__ out)
{
    const int S = CC * CC;
    int i = (blockIdx.x * 256 + threadIdx.x) * 4;
    const float* src; int base;
    if (i < 4 * S)      { src = pw;  base = 0; }
    else if (i < 6 * S) { src = wkv; base = 4 * S; }
    else if (i < 7 * S) { src = wq;  base = 6 * S; }
    else if (i < 8 * S) { src = f1;  base = 7 * S; }
    else                { src = f2;  base = 8 * S; }
    float4 f = *(const float4*)(src + (i - base));
    bfpack4 p;
    p.h[0] = (__bf16)f.x; p.h[1] = (__bf16)f.y;
    p.h[2] = (__bf16)f.z; p.h[3] = (__bf16)f.w;
    *(uint2*)(out + i) = p.v;
}

// ---------------------------------------------------------------- dw weights (NCONV,C,K) -> (NCONV,K,C) bf16
__global__ __launch_bounds__(256) void dw_transpose_kernel(
    const float* __restrict__ w, __bf16* __restrict__ wt)
{
    int t = blockIdx.x * 256 + threadIdx.x;
    if (t < NCONV * KW * CC) {
        int c = t & (CC - 1);
        int k = (t >> 9) % KW;
        int i = t / (KW * CC);
        wt[t] = (__bf16)w[(i * CC + c) * KW + k];
    }
}

// ---------------------------------------------------------------- pos enc + transpose (B,C,L) fp32 -> (B,L,C) bf16
__global__ __launch_bounds__(256) void pos_enc_t_kernel(
    const float* __restrict__ x, __bf16* __restrict__ out)
{
    __shared__ float T[64 * 65];
    const int b = blockIdx.z, c0 = blockIdx.y * 64, l0 = blockIdx.x * 64;
    const int t = threadIdx.x;
    {
        int lt = t & 63, cr0 = t >> 6;
        #pragma unroll
        for (int j = 0; j < 16; ++j) {
            int cr = cr0 + 4 * j;
            T[cr * 65 + lt] = x[((size_t)b * CC + c0 + cr) * LL + l0 + lt];
        }
    }
    __syncthreads();
    {
        int ct = t & 63, lr0 = t >> 6;
        const float log_inc = 0.03611898185f;   // log(10000)/255
        int c = c0 + ct;
        int half = (c < CC / 2) ? c : c - CC / 2;
        float inv = __expf(-log_inc * (float)half);
        #pragma unroll
        for (int j = 0; j < 16; ++j) {
            int lr = lr0 + 4 * j;
            int l = l0 + lr;
            float ph = (float)l * inv;
            float sig = (c < CC / 2) ? __sinf(ph) : __cosf(ph);
            out[((size_t)b * LL + l) * CC + c] = (__bf16)(T[ct * 65 + lr] + sig);
        }
    }
}

// ---------------------------------------------------------------- layernorm over contiguous C (bf16 in), out bf16
__global__ __launch_bounds__(256) void ln_last_kernel(
    const __bf16* __restrict__ x, const float* __restrict__ gam,
    const float* __restrict__ bet, __bf16* __restrict__ out)
{
    int row = blockIdx.x * 4 + (threadIdx.x >> 6);
    int ln = threadIdx.x & 63;
    bfpack8 xv;
    xv.v = *(const uint4*)(x + (size_t)row * CC + ln * 8);
    float v[8];
    #pragma unroll
    for (int i = 0; i < 8; ++i) v[i] = (float)xv.h[i];
    float sum = 0.f, sq = 0.f;
    #pragma unroll
    for (int i = 0; i < 8; ++i) { sum += v[i]; sq += v[i] * v[i]; }
    #pragma unroll
    for (int off = 1; off < 64; off <<= 1) {
        sum += __shfl_xor(sum, off);
        sq  += __shfl_xor(sq, off);
    }
    float mean = sum * (1.0f / CC);
    float rstd = rsqrtf(sq * (1.0f / CC) - mean * mean + 1e-5f);
    float4 g0 = *(const float4*)(gam + ln * 8);
    float4 g1 = *(const float4*)(gam + ln * 8 + 4);
    float4 b0 = *(const float4*)(bet + ln * 8);
    float4 b1 = *(const float4*)(bet + ln * 8 + 4);
    bfpack8 p;
    p.h[0] = (__bf16)((v[0] - mean) * rstd * g0.x + b0.x);
    p.h[1] = (__bf16)((v[1] - mean) * rstd * g0.y + b0.y);
    p.h[2] = (__bf16)((v[2] - mean) * rstd * g0.z + b0.z);
    p.h[3] = (__bf16)((v[3] - mean) * rstd * g0.w + b0.w);
    p.h[4] = (__bf16)((v[4] - mean) * rstd * g1.x + b1.x);
    p.h[5] = (__bf16)((v[5] - mean) * rstd * g1.y + b1.y);
    p.h[6] = (__bf16)((v[6] - mean) * rstd * g1.z + b1.z);
    p.h[7] = (__bf16)((v[7] - mean) * rstd * g1.w + b1.w);
    *(uint4*)(out + (size_t)row * CC + ln * 8) = p.v;
}

// ---------------------------------------------------------------- fused LN + depthwise conv (bf16 in, channel-last)
__global__ __launch_bounds__(256) void ln_dw_kernel(
    const __bf16* __restrict__ x, const float* __restrict__ gam,
    const float* __restrict__ bet, const __bf16* __restrict__ wt,
    __bf16* __restrict__ out)
{
    __shared__ __attribute__((aligned(16))) __bf16 Hs[40][CC];
    const int b = blockIdx.y;
    const int l0 = blockIdx.x * 32;
    const int t = threadIdx.x;
    const int w = t >> 6, ln = t & 63;

    float4 g0 = *(const float4*)(gam + ln * 8);
    float4 g1 = *(const float4*)(gam + ln * 8 + 4);
    float4 bb0 = *(const float4*)(bet + ln * 8);
    float4 bb1 = *(const float4*)(bet + ln * 8 + 4);

    #pragma unroll
    for (int p = 0; p < 10; ++p) {
        int ri = p * 4 + w;              // staged row 0..39 (global l = l0-4+ri)
        int l = l0 - 4 + ri;
        if (l < 0 || l >= LL) {          // wave-uniform branch
            uint4 z = {0u, 0u, 0u, 0u};
            *(uint4*)(&Hs[ri][ln * 8]) = z;
        } else {
            bfpack8 xv;
            xv.v = *(const uint4*)(x + ((size_t)b * LL + l) * CC + ln * 8);
            float v[8];
            #pragma unroll
            for (int i = 0; i < 8; ++i) v[i] = (float)xv.h[i];
            float sum = 0.f, sq = 0.f;
            #pragma unroll
            for (int i = 0; i < 8; ++i) { sum += v[i]; sq += v[i] * v[i]; }
            #pragma unroll
            for (int off = 1; off < 64; off <<= 1) {
                sum += __shfl_xor(sum, off);
                sq  += __shfl_xor(sq, off);
            }
            float mean = sum * (1.0f / CC);
            float rstd = rsqrtf(sq * (1.0f / CC) - mean * mean + 1e-5f);
            bfpack8 pp;
            pp.h[0] = (__bf16)((v[0] - mean) * rstd * g0.x + bb0.x);
            pp.h[1] = (__bf16)((v[1] - mean) * rstd * g0.y + bb0.y);
            pp.h[2] = (__bf16)((v[2] - mean) * rstd * g0.z + bb0.z);
            pp.h[3] = (__bf16)((v[3] - mean) * rstd * g0.w + bb0.w);
            pp.h[4] = (__bf16)((v[4] - mean) * rstd * g1.x + bb1.x);
            pp.h[5] = (__bf16)((v[5] - mean) * rstd * g1.y + bb1.y);
            pp.h[6] = (__bf16)((v[6] - mean) * rstd * g1.z + bb1.z);
            pp.h[7] = (__bf16)((v[7] - mean) * rstd * g1.w + bb1.w);
            *(uint4*)(&Hs[ri][ln * 8]) = pp.v;
        }
    }
    __syncthreads();

    const int cc0 = (t & 63) * 8;
    bfpack8 wv[KW];
    #pragma unroll
    for (int k = 0; k < KW; ++k) wv[k].v = *(const uint4*)(wt + k * CC + cc0);
    #pragma unroll
    for (int j = 0; j < 8; ++j) {
        int r = (t >> 6) + 4 * j;        // output row 0..31 (global l0+r)
        float acc[8] = {};
        #pragma unroll
        for (int k = 0; k < KW; ++k) {
            bfpack8 xv;
            xv.v = *(const uint4*)(&Hs[r + 1 + k][cc0]);
            #pragma unroll
            for (int i2 = 0; i2 < 8; ++i2)
                acc[i2] += (float)xv.h[i2] * (float)wv[k].h[i2];
        }
        bfpack8 o;
        #pragma unroll
        for (int i2 = 0; i2 < 8; ++i2) o.h[i2] = (__bf16)acc[i2];
        *(uint4*)(out + ((size_t)b * LL + l0 + r) * CC + cc0) = o.v;
    }
}

// ---------------------------------------------------------------- bf16 MFMA GEMM, 128x64 tile, BK=64 2-phase dbuf
// r12 audit: at 128x128 tiles the 512-block grid capped occupancy at 2
// blocks/CU. 128(A-rows)x64(B-rows) tiles double the grid to 1024 blocks;
// LDS = (128+64)*64*2B*2buf = 48KB -> 3 blocks/CU resident (+50% TLP).
// Wave tile 64x32 (acc[4][2]); same BK=64 issue-early/wait-late schedule +
// both-sides XOR swizzle as the r6 winner.
// mode 0: Y bf16 (B,L,C) RMW: Y = bf16(relu(acc+bias) + Y)  grid(L/64,C/128,B)
// mode 1: Y bf16 (B,L,C)  = opt-relu(acc*scale + opt bias)  grid(L/64,C/128,B)
// mode 2: swapped; Y fp32 (B,C,L) = acc+bias+res_bf16(B,L,C) grid(L/128,C/64,B)
__global__ __launch_bounds__(256) void gemm_bf_kernel(
    const __bf16* __restrict__ Wm, const __bf16* __restrict__ X,
    void* __restrict__ Yv, const float* __restrict__ bias,
    const __bf16* __restrict__ res, const int mode, const int relu,
    const float scale)
{
    const int b  = blockIdx.z;
    const int swapped = (mode >= 2);
    const int l0 = blockIdx.x * (swapped ? 128 : 64);
    const int o0 = blockIdx.y * (swapped ? 64 : 128);
    const __bf16* Xb = X + (size_t)b * LL * CC;

    __shared__ __attribute__((aligned(16))) __bf16 Al0[128 * 64];
    __shared__ __attribute__((aligned(16))) __bf16 Al1[128 * 64];
    __shared__ __attribute__((aligned(16))) __bf16 Bl0[64 * 64];
    __shared__ __attribute__((aligned(16))) __bf16 Bl1[64 * 64];

    const int tid = threadIdx.x;
    const int wave = tid >> 6, lane = tid & 63;
    const int wm = wave >> 1, wn = wave & 1;
    const int ln = lane & 15, kq = lane >> 4;

    // A = 128 rows (W non-swapped / X swapped), B = 64 rows
    const __bf16* Aptr = swapped ? (Xb + (size_t)l0 * CC) : (Wm + (size_t)o0 * CC);
    const __bf16* Bptr = swapped ? (Wm + (size_t)o0 * CC) : (Xb + (size_t)l0 * CC);

    f32x4 acc[4][2] = {};

    const int srow  = tid >> 3;                        // staged row within 32-row chunk
    const int sc    = ((tid & 7) ^ (srow & 7)) * 8;    // pre-swizzled global k-slot (elems)
    const int lbase = wave * 8 * 64;                   // wave-uniform LDS chunk (8 rows)

    auto STAGE = [&](__bf16* Ad, __bf16* Bd, int k0) {
        #pragma unroll
        for (int j = 0; j < 4; ++j)
            gload_lds16(Aptr + (size_t)(j * 32 + srow) * CC + k0 + sc,
                        Ad + j * 32 * 64 + lbase);
        #pragma unroll
        for (int j = 0; j < 2; ++j)
            gload_lds16(Bptr + (size_t)(j * 32 + srow) * CC + k0 + sc,
                        Bd + j * 32 * 64 + lbase);
    };
    auto COMPUTE = [&](const __bf16* As, const __bf16* Bs) {
        #pragma unroll
        for (int kk = 0; kk < 2; ++kk) {
            const int so = ((kk * 4 + kq) ^ (ln & 7)) * 8;   // swizzled read slot
            short8 af[4], bfr[2];
            #pragma unroll
            for (int mi = 0; mi < 4; ++mi)
                af[mi] = *(const short8*)(As + (wm * 64 + mi * 16 + ln) * 64 + so);
            #pragma unroll
            for (int ni = 0; ni < 2; ++ni)
                bfr[ni] = *(const short8*)(Bs + (wn * 32 + ni * 16 + ln) * 64 + so);
            #pragma unroll
            for (int mi = 0; mi < 4; ++mi)
                #pragma unroll
                for (int ni = 0; ni < 2; ++ni)
                    acc[mi][ni] = __builtin_amdgcn_mfma_f32_16x16x32_bf16(
                        af[mi], bfr[ni], acc[mi][ni], 0, 0, 0);
        }
    };

    STAGE(Al0, Bl0, 0);
    __syncthreads();                       // vmcnt(0) drain + barrier
    #pragma unroll
    for (int k0 = 0; k0 < CC; k0 += 128) {
        STAGE(Al1, Bl1, k0 + 64);          // issue next; latency hides under compute
        COMPUTE(Al0, Bl0);
        __syncthreads();
        if (k0 + 128 < CC) {
            STAGE(Al0, Bl0, k0 + 128);
            COMPUTE(Al1, Bl1);
            __syncthreads();
        } else {
            COMPUTE(Al1, Bl1);             // last chunk: no prefetch, no barrier
        }
    }

    if (mode == 0) {
        __bf16* Y = (__bf16*)Yv;
        #pragma unroll
        for (int mi = 0; mi < 4; ++mi) {
            int cb = o0 + wm * 64 + mi * 16 + kq * 4;
            #pragma unroll
            for (int ni = 0; ni < 2; ++ni) {
                int l = l0 + wn * 32 + ni * 16 + ln;
                size_t idx = ((size_t)b * LL + l) * CC + cb;
                bfpack4 r4; r4.v = *(const uint2*)(Y + idx);
                bfpack4 o;
                o.h[0] = (__bf16)(fmaxf(acc[mi][ni][0] + bias[cb + 0], 0.f) + (float)r4.h[0]);
                o.h[1] = (__bf16)(fmaxf(acc[mi][ni][1] + bias[cb + 1], 0.f) + (float)r4.h[1]);
                o.h[2] = (__bf16)(fmaxf(acc[mi][ni][2] + bias[cb + 2], 0.f) + (float)r4.h[2]);
                o.h[3] = (__bf16)(fmaxf(acc[mi][ni][3] + bias[cb + 3], 0.f) + (float)r4.h[3]);
                *(uint2*)(Y + idx) = o.v;
            }
        }
    } else if (mode == 1) {
        __bf16* Y = (__bf16*)Yv;
        #pragma unroll
        for (int mi = 0; mi < 4; ++mi) {
            int cb = o0 + wm * 64 + mi * 16 + kq * 4;
            #pragma unroll
            for (int ni = 0; ni < 2; ++ni) {
                int l = l0 + wn * 32 + ni * 16 + ln;
                bfpack4 p;
                #pragma unroll
                for (int i = 0; i < 4; ++i) {
                    float v = acc[mi][ni][i] * scale;
                    if (bias) v += bias[cb + i];
                    if (relu) v = fmaxf(v, 0.f);
                    p.h[i] = (__bf16)v;
                }
                *(uint2*)(Y + ((size_t)b * LL + l) * CC + cb) = p.v;
            }
        }
    } else {
        float* Y = (float*)Yv;
        #pragma unroll
        for (int mi = 0; mi < 4; ++mi) {
            int lb = l0 + wm * 64 + mi * 16 + kq * 4;
            #pragma unroll
            for (int ni = 0; ni < 2; ++ni) {
                int c = o0 + wn * 32 + ni * 16 + ln;
                float bv = bias[c];
                const __bf16* rp = res + ((size_t)b * LL + lb) * CC + c;
                float4 v;
                v.x = acc[mi][ni][0] + bv + (float)rp[0 * CC];
                v.y = acc[mi][ni][1] + bv + (float)rp[1 * CC];
                v.z = acc[mi][ni][2] + bv + (float)rp[2 * CC];
                v.w = acc[mi][ni][3] + bv + (float)rp[3 * CC];
                *(float4*)(Y + ((size_t)b * CC + c) * LL + lb) = v;
            }
        }
    }
}

// ---------------------------------------------------------------- fused QKV projection, BK=32 double-buffer
// (r9 winner: 32KB LDS -> 5 blocks/CU matches the 1536-block grid)
__global__ __launch_bounds__(256) void qkv_gemm_kernel(
    const __bf16* __restrict__ wkv, const __bf16* __restrict__ wq,
    const __bf16* __restrict__ X, __bf16* __restrict__ kout,
    __bf16* __restrict__ vout, __bf16* __restrict__ qout)
{
    const int b  = blockIdx.z;
    const int l0 = blockIdx.x * 128;
    const int sel = blockIdx.y >> 2;
    const int o0 = (blockIdx.y & 3) * 128;
    const __bf16* Xb = X + (size_t)b * LL * CC;
    const __bf16* Wsel = (sel == 0) ? wkv : (sel == 1 ? wkv + CC * CC : wq);

    __shared__ __attribute__((aligned(16))) __bf16 Al0[128 * 32];
    __shared__ __attribute__((aligned(16))) __bf16 Al1[128 * 32];
    __shared__ __attribute__((aligned(16))) __bf16 Bl0[128 * 32];
    __shared__ __attribute__((aligned(16))) __bf16 Bl1[128 * 32];

    const int tid = threadIdx.x;
    const int wave = tid >> 6, lane = tid & 63;
    const int wm = wave >> 1, wn = wave & 1;
    const int ln = lane & 15, kq = lane >> 4;

    const int swapped = (sel == 1);
    const __bf16* Aptr = swapped ? (Xb + (size_t)l0 * CC) : (Wsel + (size_t)o0 * CC);
    const __bf16* Bptr = swapped ? (Wsel + (size_t)o0 * CC) : (Xb + (size_t)l0 * CC);

    f32x4 acc[4][4] = {};

    const int srow = tid >> 2;
    const int gs   = ((tid & 3) ^ ((tid >> 3) & 3)) * 8;

    auto STAGE = [&](__bf16* Ad, __bf16* Bd, int k0) {
        gload_lds16(Aptr + (size_t)srow * CC + k0 + gs,        Ad + wave * 512);
        gload_lds16(Aptr + (size_t)(srow + 64) * CC + k0 + gs, Ad + 2048 + wave * 512);
        gload_lds16(Bptr + (size_t)srow * CC + k0 + gs,        Bd + wave * 512);
        gload_lds16(Bptr + (size_t)(srow + 64) * CC + k0 + gs, Bd + 2048 + wave * 512);
    };
    auto COMPUTE = [&](const __bf16* As, const __bf16* Bs) {
        const int so = (kq ^ ((ln >> 1) & 3)) * 8;
        short8 af[4], bfr[4];
        #pragma unroll
        for (int mi = 0; mi < 4; ++mi)
            af[mi] = *(const short8*)(As + (wm * 64 + mi * 16 + ln) * 32 + so);
        #pragma unroll
        for (int ni = 0; ni < 4; ++ni)
            bfr[ni] = *(const short8*)(Bs + (wn * 64 + ni * 16 + ln) * 32 + so);
        #pragma unroll
        for (int mi = 0; mi < 4; ++mi)
            #pragma unroll
            for (int ni = 0; ni < 4; ++ni)
                acc[mi][ni] = __builtin_amdgcn_mfma_f32_16x16x32_bf16(
                    af[mi], bfr[ni], acc[mi][ni], 0, 0, 0);
    };

    STAGE(Al0, Bl0, 0);
    __syncthreads();
    #pragma unroll
    for (int s = 0; s < 16; ++s) {
        __bf16* An = (s & 1) ? Al0 : Al1;
        __bf16* Bn = (s & 1) ? Bl0 : Bl1;
        const __bf16* Ac = (s & 1) ? Al1 : Al0;
        const __bf16* Bc = (s & 1) ? Bl1 : Bl0;
        if (s < 15) STAGE(An, Bn, (s + 1) * 32);
        COMPUTE(Ac, Bc);
        if (s < 15) __syncthreads();
    }

    if (sel == 1) {
        // V: (B,C,L) bf16, swapped mapping
        #pragma unroll
        for (int mi = 0; mi < 4; ++mi) {
            int lb = l0 + wm * 64 + mi * 16 + kq * 4;
            #pragma unroll
            for (int ni = 0; ni < 4; ++ni) {
                int c = o0 + wn * 64 + ni * 16 + ln;
                bfpack4 p;
                #pragma unroll
                for (int i = 0; i < 4; ++i) p.h[i] = (__bf16)acc[mi][ni][i];
                *(uint2*)(vout + ((size_t)b * CC + c) * LL + lb) = p.v;
            }
        }
    } else {
        __bf16* Y = (sel == 0) ? kout : qout;
        // Q carries 1/sqrt(DH) * log2(e) so attn softmax runs in exp2 domain
        const float scale = (sel == 0) ? 1.0f : 0.18033688011f;
        #pragma unroll
        for (int mi = 0; mi < 4; ++mi) {
            int cb = o0 + wm * 64 + mi * 16 + kq * 4;
            #pragma unroll
            for (int ni = 0; ni < 4; ++ni) {
                int l = l0 + wn * 64 + ni * 16 + ln;
                bfpack4 p;
                #pragma unroll
                for (int i = 0; i < 4; ++i)
                    p.h[i] = (__bf16)(acc[mi][ni][i] * scale);
                *(uint2*)(Y + ((size_t)b * LL + l) * CC + cb) = p.v;
            }
        }
    }
}

// ---------------------------------------------------------------- MFMA flash attention (r6/r9 winner)
// swapped-QK^T, single-buffer stride-64 swizzled LDS (24KB), reg-staged K/V.
// Epilogue RMW on the bf16 residual stream.
__global__ __launch_bounds__(256) void attn_mfma_kernel(
    const __bf16* __restrict__ qb, const __bf16* __restrict__ kb,
    const __bf16* __restrict__ vb, const int* __restrict__ maskp,
    __bf16* __restrict__ outp)
{
    const int b = blockIdx.z, hh = blockIdx.y, ql0 = blockIdx.x * 64;
    const int tid = threadIdx.x, w = tid >> 6, lane = tid & 63;
    const int ln = lane & 15, kq = lane >> 4;

    __shared__ __attribute__((aligned(16))) __bf16 Kl[64 * 64];   // [m][d] swizzled
    __shared__ __attribute__((aligned(16))) __bf16 Vl[64 * 64];   // [d][m] swizzled
    __shared__ __attribute__((aligned(16))) __bf16 Pl[64 * 64];   // [q][m] swizzled

    const int co = hh * 64;
    const int sr = tid >> 3, slot = tid & 7;         // staging row (0..31)+32j, 16B slot
    const int wslot = slot ^ (sr & 7);               // swizzled LDS write slot (32&7==0)

    // Q fragment in registers: lane's q-row = w*16+ln, d-slices kq*8 (+c*32)
    short8 qf[2];
    #pragma unroll
    for (int c = 0; c < 2; ++c)
        qf[c] = *(const short8*)(qb + ((size_t)b * LL + ql0 + w * 16 + ln) * CC
                                 + co + c * 32 + kq * 8);

    float l_run = 0.f;
    f32x4 oacc[4] = {};

    // linear (coalesced) global reads; swizzle applied at the LDS write
    uint4 kv0, kv1, vv0, vv1;
    kv0 = *(const uint4*)(kb + ((size_t)b * LL + sr) * CC + co + slot * 8);
    kv1 = *(const uint4*)(kb + ((size_t)b * LL + sr + 32) * CC + co + slot * 8);
    vv0 = *(const uint4*)(vb + ((size_t)(b * CC + co + sr)) * LL + slot * 8);
    vv1 = *(const uint4*)(vb + ((size_t)(b * CC + co + sr + 32)) * LL + slot * 8);

    for (int m0 = 0; m0 < LL; m0 += 64) {
        __syncthreads();                     // prev tile's reads complete
        *(uint4*)(Kl + sr * 64 + wslot * 8)        = kv0;
        *(uint4*)(Kl + (sr + 32) * 64 + wslot * 8) = kv1;
        *(uint4*)(Vl + sr * 64 + wslot * 8)        = vv0;
        *(uint4*)(Vl + (sr + 32) * 64 + wslot * 8) = vv1;
        __syncthreads();                     // tile visible
        {
            int mn = (m0 + 64 < LL) ? m0 + 64 : m0;
            kv0 = *(const uint4*)(kb + ((size_t)b * LL + mn + sr) * CC + co + slot * 8);
            kv1 = *(const uint4*)(kb + ((size_t)b * LL + mn + sr + 32) * CC + co + slot * 8);
            vv0 = *(const uint4*)(vb + ((size_t)(b * CC + co + sr)) * LL + mn + slot * 8);
            vv1 = *(const uint4*)(vb + ((size_t)(b * CC + co + sr + 32)) * LL + mn + slot * 8);
        }

        // ---- QK^T swapped: s[ni] = K_tile(ni) x Q -> S[m][q], lane: q=w*16+ln
        f32x4 s[4] = {};
        __builtin_amdgcn_s_setprio(1);
        #pragma unroll
        for (int ni = 0; ni < 4; ++ni)
            #pragma unroll
            for (int c = 0; c < 2; ++c) {
                short8 bk = *(const short8*)(Kl + (ni * 16 + ln) * 64
                                             + (((c * 4 + kq) ^ (ln & 7)) * 8));
                s[ni] = __builtin_amdgcn_mfma_f32_16x16x32_bf16(bk, qf[c], s[ni], 0, 0, 0);
            }
        __builtin_amdgcn_s_setprio(0);

        // ---- softmax numerator (exp2 domain), lane-local sum, swizzled Pl write
        #pragma unroll
        for (int ni = 0; ni < 4; ++ni) {
            int4 mv = *(const int4*)(maskp + b * LL + m0 + ni * 16 + kq * 4);
            float p0 = exp2f(mv.x ? s[ni][0] : -1e30f);
            float p1 = exp2f(mv.y ? s[ni][1] : -1e30f);
            float p2 = exp2f(mv.z ? s[ni][2] : -1e30f);
            float p3 = exp2f(mv.w ? s[ni][3] : -1e30f);
            l_run += (p0 + p1) + (p2 + p3);
            bfpack4 p4;
            p4.h[0] = (__bf16)p0; p4.h[1] = (__bf16)p1;
            p4.h[2] = (__bf16)p2; p4.h[3] = (__bf16)p3;
            // logical elems ni*16+kq*4 -> 16B slot 2ni+(kq>>1), half kq&1
            int s16 = (2 * ni + (kq >> 1)) ^ (ln & 7);
            *(uint2*)(Pl + (w * 16 + ln) * 64 + s16 * 8 + (kq & 1) * 4) = p4.v;
        }
        // wave-private exchange (wave w writes/reads rows w*16..w*16+15)
        asm volatile("s_waitcnt lgkmcnt(0)" ::: "memory");

        // ---- PV: A = V^T rows d, B = P rows q -> D[d][q]
        short8 bp[2];
        #pragma unroll
        for (int c = 0; c < 2; ++c)
            bp[c] = *(const short8*)(Pl + (w * 16 + ln) * 64
                                     + (((c * 4 + kq) ^ (ln & 7)) * 8));
        __builtin_amdgcn_s_setprio(1);
        #pragma unroll
        for (int ni = 0; ni < 4; ++ni)
            #pragma unroll
            for (int c = 0; c < 2; ++c) {
                short8 av = *(const short8*)(Vl + (ni * 16 + ln) * 64
                                             + (((c * 4 + kq) ^ (ln & 7)) * 8));
                oacc[ni] = __builtin_amdgcn_mfma_f32_16x16x32_bf16(av, bp[c], oacc[ni], 0, 0, 0);
            }
        __builtin_amdgcn_s_setprio(0);
    }

    // fold the per-kq partial sums: lanes sharing ln hold the same q
    l_run += __shfl_xor(l_run, 16);
    l_run += __shfl_xor(l_run, 32);
    float inv = 1.0f / l_run;

    int l = ql0 + w * 16 + ln;
    #pragma unroll
    for (int ni = 0; ni < 4; ++ni) {
        int c = co + ni * 16 + kq * 4;
        size_t idx = ((size_t)b * LL + l) * CC + c;
        bfpack4 r4; r4.v = *(const uint2*)(outp + idx);
        bfpack4 o;
        o.h[0] = (__bf16)((float)r4.h[0] + oacc[ni][0] * inv);
        o.h[1] = (__bf16)((float)r4.h[1] + oacc[ni][1] * inv);
        o.h[2] = (__bf16)((float)r4.h[2] + oacc[ni][2] * inv);
        o.h[3] = (__bf16)((float)r4.h[3] + oacc[ni][3] * inv);
        *(uint2*)(outp + idx) = o.v;
    }
}

// ---------------------------------------------------------------- launch
extern "C" void kernel_launch(void* const* d_in, const int* in_sizes, int n_in,
                              void* d_out, int out_size, void* d_ws, size_t ws_size,
                              hipStream_t stream)
{
    const float* inputx  = (const float*)d_in[0];
    const int*   mask    = (const int*)  d_in[1];
    const float* ncs     = (const float*)d_in[4];
    const float* ncb     = (const float*)d_in[5];
    const float* dw_w    = (const float*)d_in[6];
    const float* pw_w    = (const float*)d_in[7];
    const float* pw_b    = (const float*)d_in[8];
    const float* ln1_s   = (const float*)d_in[9];
    const float* ln1_b   = (const float*)d_in[10];
    const float* ln2_s   = (const float*)d_in[11];
    const float* ln2_b   = (const float*)d_in[12];
    const float* w_kv    = (const float*)d_in[13];
    const float* w_q     = (const float*)d_in[14];
    const float* ffn1_w  = (const float*)d_in[15];
    const float* ffn1_b  = (const float*)d_in[16];
    const float* ffn2_w  = (const float*)d_in[17];
    const float* ffn2_b  = (const float*)d_in[18];

    const size_t NT = (size_t)BB * CC * LL;
    __bf16* result = (__bf16*)d_ws;                // bf16 residual stream (B,L,C)
    __bf16* wsb  = result + NT;
    __bf16* hb   = wsb;                            // ln output (B,L,C)
    __bf16* xb   = wsb + NT;                       // dwconv out / ffn hidden
    __bf16* qbuf = wsb + 2 * NT;
    __bf16* kbuf = wsb + 3 * NT;
    __bf16* vbuf = wsb + 4 * NT;                   // (B,C,L)
    __bf16* wpw  = wsb + 5 * NT;                   // 4*C*C
    __bf16* wkv  = wpw + 4 * CC * CC;              // 2*C*C
    __bf16* wq   = wkv + 2 * CC * CC;
    __bf16* wf1  = wq + CC * CC;
    __bf16* wf2  = wf1 + CC * CC;
    __bf16* dwt  = wf2 + CC * CC;                  // 4*K*C

    dim3 blk(256);
    dim3 ggrid (LL / 64,  CC / 128, BB);   // modes 0/1: B-tile = X rows (l), 64
    dim3 ggrid2(LL / 128, CC / 64,  BB);   // mode 2: B-tile = W rows (o), 64

    // weight prep (wpw..wf2 are contiguous -> single fused convert)
    wprep_kernel<<<9 * CC * CC / 1024, blk, 0, stream>>>(pw_w, w_kv, w_q, ffn1_w, ffn2_w, wpw);
    dw_transpose_kernel<<<(NCONV * KW * CC + 255) / 256, blk, 0, stream>>>(dw_w, dwt);

    pos_enc_t_kernel<<<dim3(LL / 64, CC / 64, BB), blk, 0, stream>>>(inputx, result);

    for (int i = 0; i < NCONV; ++i) {
        ln_dw_kernel<<<dim3(LL / 32, BB), blk, 0, stream>>>(
            result, ncs + i * CC, ncb + i * CC, dwt + i * KW * CC, xb);
        gemm_bf_kernel<<<ggrid, blk, 0, stream>>>(wpw + (size_t)i * CC * CC, xb, result,
                                                  pw_b + i * CC, nullptr, 0, 1, 1.0f);
    }

    // attention
    ln_last_kernel<<<BB * LL / 4, blk, 0, stream>>>(result, ln1_s, ln1_b, hb);
    qkv_gemm_kernel<<<dim3(LL / 128, 12, BB), blk, 0, stream>>>(wkv, wq, hb, kbuf, vbuf, qbuf);
    attn_mfma_kernel<<<dim3(LL / 64, NH, BB), blk, 0, stream>>>(qbuf, kbuf, vbuf, mask, result);

    // ffn
    ln_last_kernel<<<BB * LL / 4, blk, 0, stream>>>(result, ln2_s, ln2_b, hb);
    gemm_bf_kernel<<<ggrid, blk, 0, stream>>>(wf1, hb, xb, ffn1_b, nullptr, 1, 1, 1.0f);
    gemm_bf_kernel<<<ggrid2, blk, 0, stream>>>(wf2, xb, d_out, ffn2_b, result, 2, 0, 1.0f);
}

// Round 14
// 408.874 us; speedup vs baseline: 1.0746x; 1.0746x over previous
//
#include <hip/hip_runtime.h>
#include <math.h>

#define BB 16
#define CC 512
#define LL 1024
#define NCONV 4
#define KW 7
#define NH 8
#define DH 64

typedef short short8 __attribute__((ext_vector_type(8)));
typedef float f32x4  __attribute__((ext_vector_type(4)));

union bfpack2 { __bf16 h[2]; unsigned u; };
union bfpack4 { __bf16 h[4]; uint2 v; };
union bfpack8 { __bf16 h[8]; uint4 v; };

// async global->LDS, 16B per lane. LDS dest is wave-uniform base + lane*16.
__device__ __forceinline__ void gload_lds16(const void* g, void* l) {
    __builtin_amdgcn_global_load_lds(
        (const __attribute__((address_space(1))) void*)g,
        (__attribute__((address_space(3))) void*)l, 16, 0, 0);
}

// ---------------------------------------------------------------- fused weight prep:
// pw_w(4S) | w_kv(2S) | w_q(S) | ffn1_w(S) | ffn2_w(S) -> contiguous bf16 at out
__global__ __launch_bounds__(256) void wprep_kernel(
    const float* __restrict__ pw, const float* __restrict__ wkv,
    const float* __restrict__ wq, const float* __restrict__ f1,
    const float* __restrict__ f2, __bf16* __restrict__ out)
{
    const int S = CC * CC;
    int i = (blockIdx.x * 256 + threadIdx.x) * 4;
    const float* src; int base;
    if (i < 4 * S)      { src = pw;  base = 0; }
    else if (i < 6 * S) { src = wkv; base = 4 * S; }
    else if (i < 7 * S) { src = wq;  base = 6 * S; }
    else if (i < 8 * S) { src = f1;  base = 7 * S; }
    else                { src = f2;  base = 8 * S; }
    float4 f = *(const float4*)(src + (i - base));
    bfpack4 p;
    p.h[0] = (__bf16)f.x; p.h[1] = (__bf16)f.y;
    p.h[2] = (__bf16)f.z; p.h[3] = (__bf16)f.w;
    *(uint2*)(out + i) = p.v;
}

// ---------------------------------------------------------------- dw weights (NCONV,C,K) -> (NCONV,K,C) bf16
__global__ __launch_bounds__(256) void dw_transpose_kernel(
    const float* __restrict__ w, __bf16* __restrict__ wt)
{
    int t = blockIdx.x * 256 + threadIdx.x;
    if (t < NCONV * KW * CC) {
        int c = t & (CC - 1);
        int k = (t >> 9) % KW;
        int i = t / (KW * CC);
        wt[t] = (__bf16)w[(i * CC + c) * KW + k];
    }
}

// ---------------------------------------------------------------- pos enc + transpose (B,C,L) fp32 -> (B,L,C) bf16
__global__ __launch_bounds__(256) void pos_enc_t_kernel(
    const float* __restrict__ x, __bf16* __restrict__ out)
{
    __shared__ float T[64 * 65];
    const int b = blockIdx.z, c0 = blockIdx.y * 64, l0 = blockIdx.x * 64;
    const int t = threadIdx.x;
    {
        int lt = t & 63, cr0 = t >> 6;
        #pragma unroll
        for (int j = 0; j < 16; ++j) {
            int cr = cr0 + 4 * j;
            T[cr * 65 + lt] = x[((size_t)b * CC + c0 + cr) * LL + l0 + lt];
        }
    }
    __syncthreads();
    {
        int ct = t & 63, lr0 = t >> 6;
        const float log_inc = 0.03611898185f;   // log(10000)/255
        int c = c0 + ct;
        int half = (c < CC / 2) ? c : c - CC / 2;
        float inv = __expf(-log_inc * (float)half);
        #pragma unroll
        for (int j = 0; j < 16; ++j) {
            int lr = lr0 + 4 * j;
            int l = l0 + lr;
            float ph = (float)l * inv;
            float sig = (c < CC / 2) ? __sinf(ph) : __cosf(ph);
            out[((size_t)b * LL + l) * CC + c] = (__bf16)(T[ct * 65 + lr] + sig);
        }
    }
}

// ---------------------------------------------------------------- layernorm over contiguous C (bf16 in), out bf16
__global__ __launch_bounds__(256) void ln_last_kernel(
    const __bf16* __restrict__ x, const float* __restrict__ gam,
    const float* __restrict__ bet, __bf16* __restrict__ out)
{
    int row = blockIdx.x * 4 + (threadIdx.x >> 6);
    int ln = threadIdx.x & 63;
    bfpack8 xv;
    xv.v = *(const uint4*)(x + (size_t)row * CC + ln * 8);
    float v[8];
    #pragma unroll
    for (int i = 0; i < 8; ++i) v[i] = (float)xv.h[i];
    float sum = 0.f, sq = 0.f;
    #pragma unroll
    for (int i = 0; i < 8; ++i) { sum += v[i]; sq += v[i] * v[i]; }
    #pragma unroll
    for (int off = 1; off < 64; off <<= 1) {
        sum += __shfl_xor(sum, off);
        sq  += __shfl_xor(sq, off);
    }
    float mean = sum * (1.0f / CC);
    float rstd = rsqrtf(sq * (1.0f / CC) - mean * mean + 1e-5f);
    float4 g0 = *(const float4*)(gam + ln * 8);
    float4 g1 = *(const float4*)(gam + ln * 8 + 4);
    float4 b0 = *(const float4*)(bet + ln * 8);
    float4 b1 = *(const float4*)(bet + ln * 8 + 4);
    bfpack8 p;
    p.h[0] = (__bf16)((v[0] - mean) * rstd * g0.x + b0.x);
    p.h[1] = (__bf16)((v[1] - mean) * rstd * g0.y + b0.y);
    p.h[2] = (__bf16)((v[2] - mean) * rstd * g0.z + b0.z);
    p.h[3] = (__bf16)((v[3] - mean) * rstd * g0.w + b0.w);
    p.h[4] = (__bf16)((v[4] - mean) * rstd * g1.x + b1.x);
    p.h[5] = (__bf16)((v[5] - mean) * rstd * g1.y + b1.y);
    p.h[6] = (__bf16)((v[6] - mean) * rstd * g1.z + b1.z);
    p.h[7] = (__bf16)((v[7] - mean) * rstd * g1.w + b1.w);
    *(uint4*)(out + (size_t)row * CC + ln * 8) = p.v;
}

// ---------------------------------------------------------------- fused LN + depthwise conv (bf16 in, channel-last)
__global__ __launch_bounds__(256) void ln_dw_kernel(
    const __bf16* __restrict__ x, const float* __restrict__ gam,
    const float* __restrict__ bet, const __bf16* __restrict__ wt,
    __bf16* __restrict__ out)
{
    __shared__ __attribute__((aligned(16))) __bf16 Hs[40][CC];
    const int b = blockIdx.y;
    const int l0 = blockIdx.x * 32;
    const int t = threadIdx.x;
    const int w = t >> 6, ln = t & 63;

    float4 g0 = *(const float4*)(gam + ln * 8);
    float4 g1 = *(const float4*)(gam + ln * 8 + 4);
    float4 bb0 = *(const float4*)(bet + ln * 8);
    float4 bb1 = *(const float4*)(bet + ln * 8 + 4);

    #pragma unroll
    for (int p = 0; p < 10; ++p) {
        int ri = p * 4 + w;              // staged row 0..39 (global l = l0-4+ri)
        int l = l0 - 4 + ri;
        if (l < 0 || l >= LL) {          // wave-uniform branch
            uint4 z = {0u, 0u, 0u, 0u};
            *(uint4*)(&Hs[ri][ln * 8]) = z;
        } else {
            bfpack8 xv;
            xv.v = *(const uint4*)(x + ((size_t)b * LL + l) * CC + ln * 8);
            float v[8];
            #pragma unroll
            for (int i = 0; i < 8; ++i) v[i] = (float)xv.h[i];
            float sum = 0.f, sq = 0.f;
            #pragma unroll
            for (int i = 0; i < 8; ++i) { sum += v[i]; sq += v[i] * v[i]; }
            #pragma unroll
            for (int off = 1; off < 64; off <<= 1) {
                sum += __shfl_xor(sum, off);
                sq  += __shfl_xor(sq, off);
            }
            float mean = sum * (1.0f / CC);
            float rstd = rsqrtf(sq * (1.0f / CC) - mean * mean + 1e-5f);
            bfpack8 pp;
            pp.h[0] = (__bf16)((v[0] - mean) * rstd * g0.x + bb0.x);
            pp.h[1] = (__bf16)((v[1] - mean) * rstd * g0.y + bb0.y);
            pp.h[2] = (__bf16)((v[2] - mean) * rstd * g0.z + bb0.z);
            pp.h[3] = (__bf16)((v[3] - mean) * rstd * g0.w + bb0.w);
            pp.h[4] = (__bf16)((v[4] - mean) * rstd * g1.x + bb1.x);
            pp.h[5] = (__bf16)((v[5] - mean) * rstd * g1.y + bb1.y);
            pp.h[6] = (__bf16)((v[6] - mean) * rstd * g1.z + bb1.z);
            pp.h[7] = (__bf16)((v[7] - mean) * rstd * g1.w + bb1.w);
            *(uint4*)(&Hs[ri][ln * 8]) = pp.v;
        }
    }
    __syncthreads();

    const int cc0 = (t & 63) * 8;
    bfpack8 wv[KW];
    #pragma unroll
    for (int k = 0; k < KW; ++k) wv[k].v = *(const uint4*)(wt + k * CC + cc0);
    #pragma unroll
    for (int j = 0; j < 8; ++j) {
        int r = (t >> 6) + 4 * j;        // output row 0..31 (global l0+r)
        float acc[8] = {};
        #pragma unroll
        for (int k = 0; k < KW; ++k) {
            bfpack8 xv;
            xv.v = *(const uint4*)(&Hs[r + 1 + k][cc0]);
            #pragma unroll
            for (int i2 = 0; i2 < 8; ++i2)
                acc[i2] += (float)xv.h[i2] * (float)wv[k].h[i2];
        }
        bfpack8 o;
        #pragma unroll
        for (int i2 = 0; i2 < 8; ++i2) o.h[i2] = (__bf16)acc[i2];
        *(uint4*)(out + ((size_t)b * LL + l0 + r) * CC + cc0) = o.v;
    }
}

// ---------------------------------------------------------------- bf16 MFMA GEMM, 128x128, BK=64 2-phase dbuf
// (r12 winner restored after 128x64 regressed: smaller tiles cost 1.5x staging
// per output + half the MFMA per barrier; TLP didn't compensate.)
// + T1 XCD-aware chunked block swizzle: grid (8,4,16)=512 blocks, nwg%8==0 ->
// bijective; puts the 8 x-blocks sharing a W-panel on one XCD's L2.
// mode 0: Y bf16 (B,L,C) RMW: Y = bf16(relu(acc+bias) + Y)
// mode 1: Y bf16 (B,L,C)  = opt-relu(acc*scale + opt bias)
// mode 2: swapped; Y fp32 (B,C,L) = acc + bias + res_bf16(B,L,C)
__global__ __launch_bounds__(256) void gemm_bf_kernel(
    const __bf16* __restrict__ Wm, const __bf16* __restrict__ X,
    void* __restrict__ Yv, const float* __restrict__ bias,
    const __bf16* __restrict__ res, const int mode, const int relu,
    const float scale)
{
    // XCD swizzle: grid is (8,4,16); linear id -> chunked remap -> (bx,by,b)
    int id = blockIdx.x + 8 * (blockIdx.y + 4 * blockIdx.z);
    id = (id & 7) * 64 + (id >> 3);        // nwg=512, chunk=64 per XCD
    const int bx = id & 7;
    const int by = (id >> 3) & 3;
    const int b  = id >> 5;

    const int l0 = bx * 128;
    const int o0 = by * 128;
    const __bf16* Xb = X + (size_t)b * LL * CC;

    __shared__ __attribute__((aligned(16))) __bf16 Al0[128 * 64];
    __shared__ __attribute__((aligned(16))) __bf16 Al1[128 * 64];
    __shared__ __attribute__((aligned(16))) __bf16 Bl0[128 * 64];
    __shared__ __attribute__((aligned(16))) __bf16 Bl1[128 * 64];

    const int tid = threadIdx.x;
    const int wave = tid >> 6, lane = tid & 63;
    const int wm = wave >> 1, wn = wave & 1;
    const int ln = lane & 15, kq = lane >> 4;

    const int swapped = (mode >= 2);
    const __bf16* Aptr = swapped ? (Xb + (size_t)l0 * CC) : (Wm + (size_t)o0 * CC);
    const __bf16* Bptr = swapped ? (Wm + (size_t)o0 * CC) : (Xb + (size_t)l0 * CC);

    f32x4 acc[4][4] = {};

    const int srow  = tid >> 3;                        // staged row within 32-row chunk
    const int sc    = ((tid & 7) ^ (srow & 7)) * 8;    // pre-swizzled global k-slot (elems)
    const int lbase = wave * 8 * 64;                   // wave-uniform LDS chunk (8 rows)

    auto STAGE = [&](__bf16* Ad, __bf16* Bd, int k0) {
        #pragma unroll
        for (int j = 0; j < 4; ++j) {
            gload_lds16(Aptr + (size_t)(j * 32 + srow) * CC + k0 + sc,
                        Ad + j * 32 * 64 + lbase);
            gload_lds16(Bptr + (size_t)(j * 32 + srow) * CC + k0 + sc,
                        Bd + j * 32 * 64 + lbase);
        }
    };
    auto COMPUTE = [&](const __bf16* As, const __bf16* Bs) {
        #pragma unroll
        for (int kk = 0; kk < 2; ++kk) {
            const int so = ((kk * 4 + kq) ^ (ln & 7)) * 8;   // swizzled read slot
            short8 af[4], bfr[4];
            #pragma unroll
            for (int mi = 0; mi < 4; ++mi)
                af[mi] = *(const short8*)(As + (wm * 64 + mi * 16 + ln) * 64 + so);
            #pragma unroll
            for (int ni = 0; ni < 4; ++ni)
                bfr[ni] = *(const short8*)(Bs + (wn * 64 + ni * 16 + ln) * 64 + so);
            #pragma unroll
            for (int mi = 0; mi < 4; ++mi)
                #pragma unroll
                for (int ni = 0; ni < 4; ++ni)
                    acc[mi][ni] = __builtin_amdgcn_mfma_f32_16x16x32_bf16(
                        af[mi], bfr[ni], acc[mi][ni], 0, 0, 0);
        }
    };

    STAGE(Al0, Bl0, 0);
    __syncthreads();                       // vmcnt(0) drain + barrier
    #pragma unroll
    for (int k0 = 0; k0 < CC; k0 += 128) {
        STAGE(Al1, Bl1, k0 + 64);          // issue next; latency hides under compute
        COMPUTE(Al0, Bl0);
        __syncthreads();
        if (k0 + 128 < CC) {
            STAGE(Al0, Bl0, k0 + 128);
            COMPUTE(Al1, Bl1);
            __syncthreads();
        } else {
            COMPUTE(Al1, Bl1);             // last chunk: no prefetch, no barrier
        }
    }

    if (mode == 0) {
        __bf16* Y = (__bf16*)Yv;
        #pragma unroll
        for (int mi = 0; mi < 4; ++mi) {
            int cb = o0 + wm * 64 + mi * 16 + kq * 4;
            #pragma unroll
            for (int ni = 0; ni < 4; ++ni) {
                int l = l0 + wn * 64 + ni * 16 + ln;
                size_t idx = ((size_t)b * LL + l) * CC + cb;
                bfpack4 r4; r4.v = *(const uint2*)(Y + idx);
                bfpack4 o;
                o.h[0] = (__bf16)(fmaxf(acc[mi][ni][0] + bias[cb + 0], 0.f) + (float)r4.h[0]);
                o.h[1] = (__bf16)(fmaxf(acc[mi][ni][1] + bias[cb + 1], 0.f) + (float)r4.h[1]);
                o.h[2] = (__bf16)(fmaxf(acc[mi][ni][2] + bias[cb + 2], 0.f) + (float)r4.h[2]);
                o.h[3] = (__bf16)(fmaxf(acc[mi][ni][3] + bias[cb + 3], 0.f) + (float)r4.h[3]);
                *(uint2*)(Y + idx) = o.v;
            }
        }
    } else if (mode == 1) {
        __bf16* Y = (__bf16*)Yv;
        #pragma unroll
        for (int mi = 0; mi < 4; ++mi) {
            int cb = o0 + wm * 64 + mi * 16 + kq * 4;
            #pragma unroll
            for (int ni = 0; ni < 4; ++ni) {
                int l = l0 + wn * 64 + ni * 16 + ln;
                bfpack4 p;
                #pragma unroll
                for (int i = 0; i < 4; ++i) {
                    float v = acc[mi][ni][i] * scale;
                    if (bias) v += bias[cb + i];
                    if (relu) v = fmaxf(v, 0.f);
                    p.h[i] = (__bf16)v;
                }
                *(uint2*)(Y + ((size_t)b * LL + l) * CC + cb) = p.v;
            }
        }
    } else {
        float* Y = (float*)Yv;
        #pragma unroll
        for (int mi = 0; mi < 4; ++mi) {
            int lb = l0 + wm * 64 + mi * 16 + kq * 4;
            #pragma unroll
            for (int ni = 0; ni < 4; ++ni) {
                int c = o0 + wn * 64 + ni * 16 + ln;
                float bv = bias[c];
                const __bf16* rp = res + ((size_t)b * LL + lb) * CC + c;
                float4 v;
                v.x = acc[mi][ni][0] + bv + (float)rp[0 * CC];
                v.y = acc[mi][ni][1] + bv + (float)rp[1 * CC];
                v.z = acc[mi][ni][2] + bv + (float)rp[2 * CC];
                v.w = acc[mi][ni][3] + bv + (float)rp[3 * CC];
                *(float4*)(Y + ((size_t)b * CC + c) * LL + lb) = v;
            }
        }
    }
}

// ---------------------------------------------------------------- fused QKV projection, BK=32 double-buffer
// (r9 winner) + T1 XCD swizzle: grid (8,12,16)=1536, nwg%8==0 -> bijective.
__global__ __launch_bounds__(256) void qkv_gemm_kernel(
    const __bf16* __restrict__ wkv, const __bf16* __restrict__ wq,
    const __bf16* __restrict__ X, __bf16* __restrict__ kout,
    __bf16* __restrict__ vout, __bf16* __restrict__ qout)
{
    // XCD swizzle: linear id over (8,12,16), chunk = 1536/8 = 192
    int id = blockIdx.x + 8 * (blockIdx.y + 12 * blockIdx.z);
    id = (id & 7) * 192 + (id >> 3);
    const int bx = id & 7;
    int rem = id >> 3;
    const int by = rem % 12;
    const int b  = rem / 12;

    const int l0 = bx * 128;
    const int sel = by >> 2;
    const int o0 = (by & 3) * 128;
    const __bf16* Xb = X + (size_t)b * LL * CC;
    const __bf16* Wsel = (sel == 0) ? wkv : (sel == 1 ? wkv + CC * CC : wq);

    __shared__ __attribute__((aligned(16))) __bf16 Al0[128 * 32];
    __shared__ __attribute__((aligned(16))) __bf16 Al1[128 * 32];
    __shared__ __attribute__((aligned(16))) __bf16 Bl0[128 * 32];
    __shared__ __attribute__((aligned(16))) __bf16 Bl1[128 * 32];

    const int tid = threadIdx.x;
    const int wave = tid >> 6, lane = tid & 63;
    const int wm = wave >> 1, wn = wave & 1;
    const int ln = lane & 15, kq = lane >> 4;

    const int swapped = (sel == 1);
    const __bf16* Aptr = swapped ? (Xb + (size_t)l0 * CC) : (Wsel + (size_t)o0 * CC);
    const __bf16* Bptr = swapped ? (Wsel + (size_t)o0 * CC) : (Xb + (size_t)l0 * CC);

    f32x4 acc[4][4] = {};

    const int srow = tid >> 2;
    const int gs   = ((tid & 3) ^ ((tid >> 3) & 3)) * 8;

    auto STAGE = [&](__bf16* Ad, __bf16* Bd, int k0) {
        gload_lds16(Aptr + (size_t)srow * CC + k0 + gs,        Ad + wave * 512);
        gload_lds16(Aptr + (size_t)(srow + 64) * CC + k0 + gs, Ad + 2048 + wave * 512);
        gload_lds16(Bptr + (size_t)srow * CC + k0 + gs,        Bd + wave * 512);
        gload_lds16(Bptr + (size_t)(srow + 64) * CC + k0 + gs, Bd + 2048 + wave * 512);
    };
    auto COMPUTE = [&](const __bf16* As, const __bf16* Bs) {
        const int so = (kq ^ ((ln >> 1) & 3)) * 8;
        short8 af[4], bfr[4];
        #pragma unroll
        for (int mi = 0; mi < 4; ++mi)
            af[mi] = *(const short8*)(As + (wm * 64 + mi * 16 + ln) * 32 + so);
        #pragma unroll
        for (int ni = 0; ni < 4; ++ni)
            bfr[ni] = *(const short8*)(Bs + (wn * 64 + ni * 16 + ln) * 32 + so);
        #pragma unroll
        for (int mi = 0; mi < 4; ++mi)
            #pragma unroll
            for (int ni = 0; ni < 4; ++ni)
                acc[mi][ni] = __builtin_amdgcn_mfma_f32_16x16x32_bf16(
                    af[mi], bfr[ni], acc[mi][ni], 0, 0, 0);
    };

    STAGE(Al0, Bl0, 0);
    __syncthreads();
    #pragma unroll
    for (int s = 0; s < 16; ++s) {
        __bf16* An = (s & 1) ? Al0 : Al1;
        __bf16* Bn = (s & 1) ? Bl0 : Bl1;
        const __bf16* Ac = (s & 1) ? Al1 : Al0;
        const __bf16* Bc = (s & 1) ? Bl1 : Bl0;
        if (s < 15) STAGE(An, Bn, (s + 1) * 32);
        COMPUTE(Ac, Bc);
        if (s < 15) __syncthreads();
    }

    if (sel == 1) {
        // V: (B,C,L) bf16, swapped mapping
        #pragma unroll
        for (int mi = 0; mi < 4; ++mi) {
            int lb = l0 + wm * 64 + mi * 16 + kq * 4;
            #pragma unroll
            for (int ni = 0; ni < 4; ++ni) {
                int c = o0 + wn * 64 + ni * 16 + ln;
                bfpack4 p;
                #pragma unroll
                for (int i = 0; i < 4; ++i) p.h[i] = (__bf16)acc[mi][ni][i];
                *(uint2*)(vout + ((size_t)b * CC + c) * LL + lb) = p.v;
            }
        }
    } else {
        __bf16* Y = (sel == 0) ? kout : qout;
        // Q carries 1/sqrt(DH) * log2(e) so attn softmax runs in exp2 domain
        const float scale = (sel == 0) ? 1.0f : 0.18033688011f;
        #pragma unroll
        for (int mi = 0; mi < 4; ++mi) {
            int cb = o0 + wm * 64 + mi * 16 + kq * 4;
            #pragma unroll
            for (int ni = 0; ni < 4; ++ni) {
                int l = l0 + wn * 64 + ni * 16 + ln;
                bfpack4 p;
                #pragma unroll
                for (int i = 0; i < 4; ++i)
                    p.h[i] = (__bf16)(acc[mi][ni][i] * scale);
                *(uint2*)(Y + ((size_t)b * LL + l) * CC + cb) = p.v;
            }
        }
    }
}

// ---------------------------------------------------------------- MFMA flash attention (r6/r9 winner)
// swapped-QK^T, single-buffer stride-64 swizzled LDS (24KB), reg-staged K/V.
// Epilogue RMW on the bf16 residual stream.
__global__ __launch_bounds__(256) void attn_mfma_kernel(
    const __bf16* __restrict__ qb, const __bf16* __restrict__ kb,
    const __bf16* __restrict__ vb, const int* __restrict__ maskp,
    __bf16* __restrict__ outp)
{
    const int b = blockIdx.z, hh = blockIdx.y, ql0 = blockIdx.x * 64;
    const int tid = threadIdx.x, w = tid >> 6, lane = tid & 63;
    const int ln = lane & 15, kq = lane >> 4;

    __shared__ __attribute__((aligned(16))) __bf16 Kl[64 * 64];   // [m][d] swizzled
    __shared__ __attribute__((aligned(16))) __bf16 Vl[64 * 64];   // [d][m] swizzled
    __shared__ __attribute__((aligned(16))) __bf16 Pl[64 * 64];   // [q][m] swizzled

    const int co = hh * 64;
    const int sr = tid >> 3, slot = tid & 7;         // staging row (0..31)+32j, 16B slot
    const int wslot = slot ^ (sr & 7);               // swizzled LDS write slot (32&7==0)

    // Q fragment in registers: lane's q-row = w*16+ln, d-slices kq*8 (+c*32)
    short8 qf[2];
    #pragma unroll
    for (int c = 0; c < 2; ++c)
        qf[c] = *(const short8*)(qb + ((size_t)b * LL + ql0 + w * 16 + ln) * CC
                                 + co + c * 32 + kq * 8);

    float l_run = 0.f;
    f32x4 oacc[4] = {};

    // linear (coalesced) global reads; swizzle applied at the LDS write
    uint4 kv0, kv1, vv0, vv1;
    kv0 = *(const uint4*)(kb + ((size_t)b * LL + sr) * CC + co + slot * 8);
    kv1 = *(const uint4*)(kb + ((size_t)b * LL + sr + 32) * CC + co + slot * 8);
    vv0 = *(const uint4*)(vb + ((size_t)(b * CC + co + sr)) * LL + slot * 8);
    vv1 = *(const uint4*)(vb + ((size_t)(b * CC + co + sr + 32)) * LL + slot * 8);

    for (int m0 = 0; m0 < LL; m0 += 64) {
        __syncthreads();                     // prev tile's reads complete
        *(uint4*)(Kl + sr * 64 + wslot * 8)        = kv0;
        *(uint4*)(Kl + (sr + 32) * 64 + wslot * 8) = kv1;
        *(uint4*)(Vl + sr * 64 + wslot * 8)        = vv0;
        *(uint4*)(Vl + (sr + 32) * 64 + wslot * 8) = vv1;
        __syncthreads();                     // tile visible
        {
            int mn = (m0 + 64 < LL) ? m0 + 64 : m0;
            kv0 = *(const uint4*)(kb + ((size_t)b * LL + mn + sr) * CC + co + slot * 8);
            kv1 = *(const uint4*)(kb + ((size_t)b * LL + mn + sr + 32) * CC + co + slot * 8);
            vv0 = *(const uint4*)(vb + ((size_t)(b * CC + co + sr)) * LL + mn + slot * 8);
            vv1 = *(const uint4*)(vb + ((size_t)(b * CC + co + sr + 32)) * LL + mn + slot * 8);
        }

        // ---- QK^T swapped: s[ni] = K_tile(ni) x Q -> S[m][q], lane: q=w*16+ln
        f32x4 s[4] = {};
        __builtin_amdgcn_s_setprio(1);
        #pragma unroll
        for (int ni = 0; ni < 4; ++ni)
            #pragma unroll
            for (int c = 0; c < 2; ++c) {
                short8 bk = *(const short8*)(Kl + (ni * 16 + ln) * 64
                                             + (((c * 4 + kq) ^ (ln & 7)) * 8));
                s[ni] = __builtin_amdgcn_mfma_f32_16x16x32_bf16(bk, qf[c], s[ni], 0, 0, 0);
            }
        __builtin_amdgcn_s_setprio(0);

        // ---- softmax numerator (exp2 domain), lane-local sum, swizzled Pl write
        #pragma unroll
        for (int ni = 0; ni < 4; ++ni) {
            int4 mv = *(const int4*)(maskp + b * LL + m0 + ni * 16 + kq * 4);
            float p0 = exp2f(mv.x ? s[ni][0] : -1e30f);
            float p1 = exp2f(mv.y ? s[ni][1] : -1e30f);
            float p2 = exp2f(mv.z ? s[ni][2] : -1e30f);
            float p3 = exp2f(mv.w ? s[ni][3] : -1e30f);
            l_run += (p0 + p1) + (p2 + p3);
            bfpack4 p4;
            p4.h[0] = (__bf16)p0; p4.h[1] = (__bf16)p1;
            p4.h[2] = (__bf16)p2; p4.h[3] = (__bf16)p3;
            // logical elems ni*16+kq*4 -> 16B slot 2ni+(kq>>1), half kq&1
            int s16 = (2 * ni + (kq >> 1)) ^ (ln & 7);
            *(uint2*)(Pl + (w * 16 + ln) * 64 + s16 * 8 + (kq & 1) * 4) = p4.v;
        }
        // wave-private exchange (wave w writes/reads rows w*16..w*16+15)
        asm volatile("s_waitcnt lgkmcnt(0)" ::: "memory");

        // ---- PV: A = V^T rows d, B = P rows q -> D[d][q]
        short8 bp[2];
        #pragma unroll
        for (int c = 0; c < 2; ++c)
            bp[c] = *(const short8*)(Pl + (w * 16 + ln) * 64
                                     + (((c * 4 + kq) ^ (ln & 7)) * 8));
        __builtin_amdgcn_s_setprio(1);
        #pragma unroll
        for (int ni = 0; ni < 4; ++ni)
            #pragma unroll
            for (int c = 0; c < 2; ++c) {
                short8 av = *(const short8*)(Vl + (ni * 16 + ln) * 64
                                             + (((c * 4 + kq) ^ (ln & 7)) * 8));
                oacc[ni] = __builtin_amdgcn_mfma_f32_16x16x32_bf16(av, bp[c], oacc[ni], 0, 0, 0);
            }
        __builtin_amdgcn_s_setprio(0);
    }

    // fold the per-kq partial sums: lanes sharing ln hold the same q
    l_run += __shfl_xor(l_run, 16);
    l_run += __shfl_xor(l_run, 32);
    float inv = 1.0f / l_run;

    int l = ql0 + w * 16 + ln;
    #pragma unroll
    for (int ni = 0; ni < 4; ++ni) {
        int c = co + ni * 16 + kq * 4;
        size_t idx = ((size_t)b * LL + l) * CC + c;
        bfpack4 r4; r4.v = *(const uint2*)(outp + idx);
        bfpack4 o;
        o.h[0] = (__bf16)((float)r4.h[0] + oacc[ni][0] * inv);
        o.h[1] = (__bf16)((float)r4.h[1] + oacc[ni][1] * inv);
        o.h[2] = (__bf16)((float)r4.h[2] + oacc[ni][2] * inv);
        o.h[3] = (__bf16)((float)r4.h[3] + oacc[ni][3] * inv);
        *(uint2*)(outp + idx) = o.v;
    }
}

// ---------------------------------------------------------------- launch
extern "C" void kernel_launch(void* const* d_in, const int* in_sizes, int n_in,
                              void* d_out, int out_size, void* d_ws, size_t ws_size,
                              hipStream_t stream)
{
    const float* inputx  = (const float*)d_in[0];
    const int*   mask    = (const int*)  d_in[1];
    const float* ncs     = (const float*)d_in[4];
    const float* ncb     = (const float*)d_in[5];
    const float* dw_w    = (const float*)d_in[6];
    const float* pw_w    = (const float*)d_in[7];
    const float* pw_b    = (const float*)d_in[8];
    const float* ln1_s   = (const float*)d_in[9];
    const float* ln1_b   = (const float*)d_in[10];
    const float* ln2_s   = (const float*)d_in[11];
    const float* ln2_b   = (const float*)d_in[12];
    const float* w_kv    = (const float*)d_in[13];
    const float* w_q     = (const float*)d_in[14];
    const float* ffn1_w  = (const float*)d_in[15];
    const float* ffn1_b  = (const float*)d_in[16];
    const float* ffn2_w  = (const float*)d_in[17];
    const float* ffn2_b  = (const float*)d_in[18];

    const size_t NT = (size_t)BB * CC * LL;
    __bf16* result = (__bf16*)d_ws;                // bf16 residual stream (B,L,C)
    __bf16* wsb  = result + NT;
    __bf16* hb   = wsb;                            // ln output (B,L,C)
    __bf16* xb   = wsb + NT;                       // dwconv out / ffn hidden
    __bf16* qbuf = wsb + 2 * NT;
    __bf16* kbuf = wsb + 3 * NT;
    __bf16* vbuf = wsb + 4 * NT;                   // (B,C,L)
    __bf16* wpw  = wsb + 5 * NT;                   // 4*C*C
    __bf16* wkv  = wpw + 4 * CC * CC;              // 2*C*C
    __bf16* wq   = wkv + 2 * CC * CC;
    __bf16* wf1  = wq + CC * CC;
    __bf16* wf2  = wf1 + CC * CC;
    __bf16* dwt  = wf2 + CC * CC;                  // 4*K*C

    dim3 blk(256);
    dim3 ggrid(LL / 128, CC / 128, BB);

    // weight prep (wpw..wf2 are contiguous -> single fused convert)
    wprep_kernel<<<9 * CC * CC / 1024, blk, 0, stream>>>(pw_w, w_kv, w_q, ffn1_w, ffn2_w, wpw);
    dw_transpose_kernel<<<(NCONV * KW * CC + 255) / 256, blk, 0, stream>>>(dw_w, dwt);

    pos_enc_t_kernel<<<dim3(LL / 64, CC / 64, BB), blk, 0, stream>>>(inputx, result);

    for (int i = 0; i < NCONV; ++i) {
        ln_dw_kernel<<<dim3(LL / 32, BB), blk, 0, stream>>>(
            result, ncs + i * CC, ncb + i * CC, dwt + i * KW * CC, xb);
        gemm_bf_kernel<<<ggrid, blk, 0, stream>>>(wpw + (size_t)i * CC * CC, xb, result,
                                                  pw_b + i * CC, nullptr, 0, 1, 1.0f);
    }

    // attention
    ln_last_kernel<<<BB * LL / 4, blk, 0, stream>>>(result, ln1_s, ln1_b, hb);
    qkv_gemm_kernel<<<dim3(LL / 128, 12, BB), blk, 0, stream>>>(wkv, wq, hb, kbuf, vbuf, qbuf);
    attn_mfma_kernel<<<dim3(LL / 64, NH, BB), blk, 0, stream>>>(qbuf, kbuf, vbuf, mask, result);

    // ffn
    ln_last_kernel<<<BB * LL / 4, blk, 0, stream>>>(result, ln2_s, ln2_b, hb);
    gemm_bf_kernel<<<ggrid, blk, 0, stream>>>(wf1, hb, xb, ffn1_b, nullptr, 1, 1, 1.0f);
    gemm_bf_kernel<<<ggrid, blk, 0, stream>>>(wf2, xb, d_out, ffn2_b, result, 2, 0, 1.0f);
}